// Round 6
// baseline (899.572 us; speedup 1.0000x reference)
//
#include <hip/hip_runtime.h>
#include <hip/hip_bf16.h>

#define NN 100000
#define EE 500000
#define BB 4096
#define HC 128
#define SCAN_ELEM 1024
#define NSB ((NN + SCAN_ELEM - 1) / SCAN_ELEM)   // 98 blocks

typedef __bf16 bf16_t;
typedef bf16_t bf16x8 __attribute__((ext_vector_type(8)));
typedef float f32x4 __attribute__((ext_vector_type(4)));
typedef float f32x2 __attribute__((ext_vector_type(2)));

__device__ __forceinline__ unsigned short f2bf(float f) {
    unsigned u = __builtin_bit_cast(unsigned, f);
    u += 0x7FFFu + ((u >> 16) & 1u);            // RNE
    return (unsigned short)(u >> 16);
}
__device__ __forceinline__ float bflo(unsigned u) {   // low bf16 -> f32
    return __builtin_bit_cast(float, u << 16);
}
__device__ __forceinline__ float bfhi(unsigned u) {   // high bf16 -> f32
    return __builtin_bit_cast(float, u & 0xFFFF0000u);
}
__device__ __forceinline__ f32x2 unpk2(unsigned u) {  // packed pair -> 2 f32
    return (f32x2){ bflo(u), bfhi(u) };
}

// ---- convert + transpose weights: W[k,n] fp32 -> Wt[p][n*K+k] bf16 ---------
__global__ __launch_bounds__(256) void prep_w(
    const float* __restrict__ Wq, const float* __restrict__ Wk,
    const float* __restrict__ Wv, const float* __restrict__ Ws,
    unsigned short* __restrict__ Wt, int K)
{
    const int g = blockIdx.x * 256 + threadIdx.x;
    const int per = K * 128;
    if (g >= 4 * per) return;
    const int p = g / per, r = g - p * per;
    const int k = r >> 7, n = r & 127;
    const float* W = p == 0 ? Wq : p == 1 ? Wk : p == 2 ? Wv : Ws;
    Wt[(size_t)p * per + (size_t)n * K + k] = f2bf(W[k * 128 + n]);
}

// ---- MFMA GEMM: block = 4 waves = 4 planes, 32-row tile, 128 cols ----------
// ALL outputs packed bf16 (pair per dword), merged planes to cut HBM bytes:
//   QSb[node] = [ Q : 64 dwords | S(skip) : 64 dwords ]   (stride 128)
//   KVb[node] = [ K : 64 dwords | V       : 64 dwords ]   (stride 128)
// F32A=1: A is fp32 (layer-1 x), converted to bf16 fragments in-register.
template<int NKT, int F32A>
__global__ __launch_bounds__(256) void gemm_mfma(
    const unsigned short* __restrict__ Abf,
    const float* __restrict__ xf,
    const unsigned short* __restrict__ Wt,
    const float* __restrict__ bq, const float* __restrict__ bk,
    const float* __restrict__ bv, const float* __restrict__ bs,
    unsigned* __restrict__ QSb, unsigned* __restrict__ KVb)
{
    constexpr int K = NKT * 32;
    const int lane = threadIdx.x & 63;
    const int p = threadIdx.x >> 6;              // wave == plane
    const int m = lane & 15, kq = lane >> 4;
    const int rows0 = blockIdx.x * 32;

    const unsigned short* Wp = Wt + (size_t)p * 128 * K;
    const float* bias = p == 0 ? bq : p == 1 ? bk : p == 2 ? bv : bs;

    bf16x8 a[2][NKT];
#pragma unroll
    for (int mt = 0; mt < 2; mt++)
#pragma unroll
        for (int kt = 0; kt < NKT; kt++) {
            if constexpr (F32A) {
                const float* pr = xf + (size_t)(rows0 + mt * 16 + m) * K + kt * 32 + kq * 8;
                const float4 f0 = *(const float4*)pr;
                const float4 f1 = *(const float4*)(pr + 4);
                union { bf16x8 v; unsigned short u8[8]; } cv;
                cv.u8[0] = f2bf(f0.x); cv.u8[1] = f2bf(f0.y);
                cv.u8[2] = f2bf(f0.z); cv.u8[3] = f2bf(f0.w);
                cv.u8[4] = f2bf(f1.x); cv.u8[5] = f2bf(f1.y);
                cv.u8[6] = f2bf(f1.z); cv.u8[7] = f2bf(f1.w);
                a[mt][kt] = cv.v;
            } else {
                a[mt][kt] = *(const bf16x8*)(Abf + (size_t)(rows0 + mt * 16 + m) * K + kt * 32 + kq * 8);
            }
        }

    f32x4 acc[2][8];
#pragma unroll
    for (int mt = 0; mt < 2; mt++)
#pragma unroll
        for (int nt = 0; nt < 8; nt++)
            acc[mt][nt] = (f32x4){0.f, 0.f, 0.f, 0.f};

#pragma unroll
    for (int nt = 0; nt < 8; nt++) {
#pragma unroll
        for (int kt = 0; kt < NKT; kt++) {
            const bf16x8 b = *(const bf16x8*)(Wp + (size_t)(nt * 16 + m) * K + kt * 32 + kq * 8);
            acc[0][nt] = __builtin_amdgcn_mfma_f32_16x16x32_bf16(a[0][kt], b, acc[0][nt], 0, 0, 0);
            acc[1][nt] = __builtin_amdgcn_mfma_f32_16x16x32_bf16(a[1][kt], b, acc[1][nt], 0, 0, 0);
        }
    }

    unsigned* out = p == 0 ? QSb : p == 1 ? KVb : p == 2 ? (KVb + 64) : (QSb + 64);
#pragma unroll
    for (int nt = 0; nt < 8; nt++) {
        const float bi = bias[nt * 16 + m];
#pragma unroll
        for (int mt = 0; mt < 2; mt++) {
#pragma unroll
            for (int r = 0; r < 4; r++) {
                const float v0 = acc[mt][nt][r] + bi;
                const float v1 = __shfl_xor(v0, 1);
                if (!(m & 1)) {
                    const unsigned pk = (unsigned)f2bf(v0) | ((unsigned)f2bf(v1) << 16);
                    out[(size_t)(rows0 + mt * 16 + kq * 4 + r) * 128 + nt * 8 + (m >> 1)] = pk;
                }
            }
        }
    }
}

// ---- CSR build: degree histogram -> hierarchical scan -> bucket scatter -----
__global__ __launch_bounds__(256) void deg_k(const int* __restrict__ ei, int* __restrict__ deg)
{
    const int e = blockIdx.x * 256 + threadIdx.x;
    if (e < EE) atomicAdd(&deg[ei[EE + e]], 1);
}

__global__ __launch_bounds__(256) void scan_part(const int* __restrict__ deg,
                                                 int* __restrict__ bsum)
{
    __shared__ int red[256];
    const int base = blockIdx.x * SCAN_ELEM + threadIdx.x * 4;
    int s = 0;
#pragma unroll
    for (int j = 0; j < 4; j++) { const int i = base + j; if (i < NN) s += deg[i]; }
    red[threadIdx.x] = s;
    __syncthreads();
    for (int st = 128; st > 0; st >>= 1) {
        if (threadIdx.x < st) red[threadIdx.x] += red[threadIdx.x + st];
        __syncthreads();
    }
    if (threadIdx.x == 0) bsum[blockIdx.x] = red[0];
}

__global__ __launch_bounds__(128) void scan_top(const int* __restrict__ bsum,
                                                int* __restrict__ boff)
{
    __shared__ int buf[128];
    const int v = (threadIdx.x < NSB) ? bsum[threadIdx.x] : 0;
    buf[threadIdx.x] = v;
    __syncthreads();
    for (int s = 1; s < 128; s <<= 1) {
        const int t = (threadIdx.x >= s) ? buf[threadIdx.x - s] : 0;
        __syncthreads();
        buf[threadIdx.x] += t;
        __syncthreads();
    }
    if (threadIdx.x < NSB) boff[threadIdx.x] = buf[threadIdx.x] - v;
}

__global__ __launch_bounds__(256) void scan_final(const int* __restrict__ deg,
                                                  const int* __restrict__ boff,
                                                  int* __restrict__ off,
                                                  int* __restrict__ cursor)
{
    __shared__ int tsum[256];
    const int base = blockIdx.x * SCAN_ELEM + threadIdx.x * 4;
    int vals[4];
    int s = 0;
#pragma unroll
    for (int j = 0; j < 4; j++) {
        const int i = base + j;
        vals[j] = (i < NN) ? deg[i] : 0;
        s += vals[j];
    }
    tsum[threadIdx.x] = s;
    __syncthreads();
    for (int st = 1; st < 256; st <<= 1) {
        const int t = (threadIdx.x >= st) ? tsum[threadIdx.x - st] : 0;
        __syncthreads();
        tsum[threadIdx.x] += t;
        __syncthreads();
    }
    int ex = boff[blockIdx.x] + tsum[threadIdx.x] - s;
#pragma unroll
    for (int j = 0; j < 4; j++) {
        const int i = base + j;
        if (i < NN) { off[i] = ex; cursor[i] = ex; }
        ex += vals[j];
    }
    if (blockIdx.x == NSB - 1 && threadIdx.x == 255)
        off[NN] = boff[blockIdx.x] + tsum[255];
}

// bucket: write src node id AND reordered edge_attr at CSR slot.
__global__ __launch_bounds__(256) void bucket_k(const int* __restrict__ ei,
                                                const float* __restrict__ ea,
                                                int* __restrict__ cursor,
                                                int* __restrict__ esrc,
                                                float4* __restrict__ eaf)
{
    const int e = blockIdx.x * 256 + threadIdx.x;
    if (e < EE) {
        const int d = ei[EE + e];
        const int p = atomicAdd(&cursor[d], 1);
        esrc[p] = ei[e];
        eaf[p] = *(const float4*)(ea + (size_t)e * 4);
    }
}

__global__ __launch_bounds__(256) void cnt_k(const int* __restrict__ batch,
                                             float* __restrict__ cnt)
{
    const int n = blockIdx.x * 256 + threadIdx.x;
    if (n < NN) atomicAdd(&cnt[batch[n]], 1.0f);
}

// ---- Fused edge stage: one wave per dst node, EIGHT edges in flight. -------
// Lane = slot*8 + c8; slot in [0,8): edge slot; c8 in [0,8): 16 channels
// (two dwordx4 of packed bf16 at KVb[src]*128 + c8*8, V at +64 dwords).
// Per-wave in-flight gather bytes: 8 edges x 512 B = 4 KB (4x the previous
// 4-slot layout) -- the MLP/Little's-law lever; iterations/node ~1.
// Head = 32 ch = 2 lanes -> score reduce is ONE shfl_xor(1).
// Algebra (e = We.a linear): q.(K+e) = q.K + a.(We^T q); per-lane partial
// qep folds into the score reduce; sum(alpha*(V+e)) = sum(alpha*V) +
// We.(sum(alpha*a)) with running s4.
// Epilogue distributed: every lane owns 2 channels (ceq = c8*16 + slot*2).
// fuse_pool=0: out = relu(msg/den + skip) -> bf16 Hb (next GEMM input).
// fuse_pool=1: out = msg/den + skip -> atomicAdd into pooled[batch[n]].
__global__ __launch_bounds__(256) void edge_fused(
    const int* __restrict__ esrc, const float4* __restrict__ eaf,
    const float* __restrict__ We,
    const unsigned* __restrict__ QSb, const unsigned* __restrict__ KVb,
    const int* __restrict__ off,
    unsigned short* __restrict__ Hb,
    const int* __restrict__ batch, float* __restrict__ pooled,
    int fuse_pool)
{
    const int lane = threadIdx.x & 63;
    const int slot = lane >> 3;          // edge slot 0..7
    const int c8   = lane & 7;           // channel group: channels c8*16 .. +15
    const int cb   = c8 * 16;
    const int ceq  = cb + slot * 2;      // this lane's epilogue channel pair
    const int n = blockIdx.x * 4 + (threadIdx.x >> 6);

    const int2 be = *(const int2*)(off + n);     // {beg, end} one load
    const int beg = be.x, end = be.y;

    // issue independent loads early: q row (16 ch = 2 x dwordx4) + skip pair
    const uint4 qva = *(const uint4*)(QSb + (size_t)n * 128 + c8 * 8);
    const uint4 qvb = *(const uint4*)(QSb + (size_t)n * 128 + c8 * 8 + 4);
    const unsigned sku = QSb[(size_t)n * 128 + 64 + c8 * 8 + slot];
    f32x2 q2[8];
    q2[0] = unpk2(qva.x); q2[1] = unpk2(qva.y);
    q2[2] = unpk2(qva.z); q2[3] = unpk2(qva.w);
    q2[4] = unpk2(qvb.x); q2[5] = unpk2(qvb.y);
    q2[6] = unpk2(qvb.z); q2[7] = unpk2(qvb.w);

    // per-lane qe partials over my 16 channels (reduced jointly with q.K)
    float qep[4];
#pragma unroll
    for (int d = 0; d < 4; d++) {
        float acc = 0.f;
#pragma unroll
        for (int j = 0; j < 4; j++) {
            const float4 w4 = *(const float4*)(We + d * HC + cb + j * 4);
            acc += w4.x * q2[2 * j].x + w4.y * q2[2 * j].y
                 + w4.z * q2[2 * j + 1].x + w4.w * q2[2 * j + 1].y;
        }
        qep[d] = acc;
    }

    f32x2 num2[8] = {(f32x2){0.f,0.f},(f32x2){0.f,0.f},(f32x2){0.f,0.f},(f32x2){0.f,0.f},
                     (f32x2){0.f,0.f},(f32x2){0.f,0.f},(f32x2){0.f,0.f},(f32x2){0.f,0.f}};
    f32x4 s4 = (f32x4){0.f, 0.f, 0.f, 0.f};
    float den = 0.f;

    if (beg < end) {
        const int e1 = end - 1;
        int p0 = beg + slot; if (p0 > e1) p0 = e1;
        int src = esrc[p0];
        float4 a4 = eaf[p0];
        for (int base = beg; base < end; base += 8) {
            const unsigned* kv = KVb + (size_t)src * 128 + c8 * 8;
            const uint4 ka = *(const uint4*)kv;
            const uint4 kb = *(const uint4*)(kv + 4);
            const uint4 va = *(const uint4*)(kv + 64);
            const uint4 vb = *(const uint4*)(kv + 68);
            const float4 ac = a4;
            const bool act = (base + slot) < end;
            if (base + 8 < end) {                  // 1-ahead prefetch
                int pn = base + 8 + slot; if (pn > e1) pn = e1;
                src = esrc[pn]; a4 = eaf[pn];
            }
            f32x2 t2 = q2[0] * unpk2(ka.x);
            t2 += q2[1] * unpk2(ka.y);
            t2 += q2[2] * unpk2(ka.z);
            t2 += q2[3] * unpk2(ka.w);
            t2 += q2[4] * unpk2(kb.x);
            t2 += q2[5] * unpk2(kb.y);
            t2 += q2[6] * unpk2(kb.z);
            t2 += q2[7] * unpk2(kb.w);
            float tot = t2.x + t2.y
                      + ac.x * qep[0] + ac.y * qep[1] + ac.z * qep[2] + ac.w * qep[3];
            tot += __shfl_xor(tot, 1);            // 2-lane head reduce (32 ch)
            float al = __expf(tot * 0.17677669529663687f);   // 1/sqrt(32)
            if (!act) al = 0.f;
            num2[0] += unpk2(va.x) * al;
            num2[1] += unpk2(va.y) * al;
            num2[2] += unpk2(va.z) * al;
            num2[3] += unpk2(va.w) * al;
            num2[4] += unpk2(vb.x) * al;
            num2[5] += unpk2(vb.y) * al;
            num2[6] += unpk2(vb.z) * al;
            num2[7] += unpk2(vb.w) * al;
            s4.x += ac.x * al; s4.y += ac.y * al;
            s4.z += ac.z * al; s4.w += ac.w * al;
            den += al;
        }
    }

    // cross-slot combine (once per node): slots differ in lane bits 3,4,5
#pragma unroll
    for (int st = 8; st < 64; st <<= 1) {
#pragma unroll
        for (int j = 0; j < 8; j++) {
            num2[j].x += __shfl_xor(num2[j].x, st);
            num2[j].y += __shfl_xor(num2[j].y, st);
        }
        s4.x += __shfl_xor(s4.x, st); s4.y += __shfl_xor(s4.y, st);
        s4.z += __shfl_xor(s4.z, st); s4.w += __shfl_xor(s4.w, st);
        den += __shfl_xor(den, st);
    }
    const float inv = 1.f / (den + 1e-16f);

    // my channel pair (static-index selection: slot -> num2[slot>>... ])
    // lane's epilogue pair lives at num2[slot] offsets? channels cb+slot*2
    // pair index within my 16 channels = slot  -> num2[slot]
    f32x2 mynum;
    switch (slot) {
        case 0: mynum = num2[0]; break;
        case 1: mynum = num2[1]; break;
        case 2: mynum = num2[2]; break;
        case 3: mynum = num2[3]; break;
        case 4: mynum = num2[4]; break;
        case 5: mynum = num2[5]; break;
        case 6: mynum = num2[6]; break;
        default: mynum = num2[7]; break;
    }
    // edge-attr contribution for my 2 channels: We . s4
    float ev0 = 0.f, ev1 = 0.f;
#pragma unroll
    for (int d = 0; d < 4; d++) {
        const float2 wd = *(const float2*)(We + d * HC + ceq);
        const float sd = d == 0 ? s4.x : d == 1 ? s4.y : d == 2 ? s4.z : s4.w;
        ev0 += sd * wd.x;
        ev1 += sd * wd.y;
    }
    const float o0 = (mynum.x + ev0) * inv + bflo(sku);
    const float o1 = (mynum.y + ev1) * inv + bfhi(sku);

    if (!fuse_pool) {
        const float r0 = fmaxf(o0, 0.f), r1 = fmaxf(o1, 0.f);
        const unsigned pk = (unsigned)f2bf(r0) | ((unsigned)f2bf(r1) << 16);
        *(unsigned*)(Hb + (size_t)n * HC + ceq) = pk;   // 64 lanes = 256B row
    } else {
        const int b = batch[n];
        atomicAdd(pooled + (size_t)b * HC + ceq,     o0);
        atomicAdd(pooled + (size_t)b * HC + ceq + 1, o1);
    }
}

__global__ __launch_bounds__(256) void head_k(
    const float* __restrict__ pooled, const float* __restrict__ cnt,
    const int* __restrict__ rt, const float* __restrict__ hW,
    const float* __restrict__ hb, float* __restrict__ out)
{
    const int lane = threadIdx.x & 63;
    const int b = blockIdx.x * 4 + (threadIdx.x >> 6);
    if (b >= BB) return;
    const int t = rt[b];
    const int c = lane * 2;
    const float2 p2 = *(const float2*)(pooled + (size_t)b * HC + c);
    const float2 w2 = *(const float2*)(hW + (size_t)t * HC + c);
    float part = p2.x * w2.x + p2.y * w2.y;
    part += __shfl_xor(part, 1);
    part += __shfl_xor(part, 2);
    part += __shfl_xor(part, 4);
    part += __shfl_xor(part, 8);
    part += __shfl_xor(part, 16);
    part += __shfl_xor(part, 32);
    if (lane == 0) out[b] = part / fmaxf(cnt[b], 1.0f) + hb[t];
}

extern "C" void kernel_launch(void* const* d_in, const int* in_sizes, int n_in,
                              void* d_out, int out_size, void* d_ws, size_t ws_size,
                              hipStream_t stream) {
    const float* x      = (const float*)d_in[0];
    const int*   ei     = (const int*)d_in[1];
    const float* ea     = (const float*)d_in[2];
    const int*   batch  = (const int*)d_in[3];
    const int*   rt     = (const int*)d_in[4];

    // workspace layout — big 16B-aligned arrays first; ~141 MB total
    unsigned* QSb = (unsigned*)d_ws;                      // 12,800,000 u32 (Q|S bf16)
    unsigned* KVb = QSb + 12800000;                       // 12,800,000 u32 (K|V bf16)
    unsigned short* Abf = (unsigned short*)(KVb + 12800000); // 12,800,000 us (h plane)
    float4* eaf   = (float4*)(Abf + 12800000);            // 500,000 float4
    unsigned short* Wt = (unsigned short*)(eaf + 500000); // 65,536 us
    float* pooled = (float*)(Wt + 65536);                 // 524,288 f
    float* cnt    = pooled + 524288;                      // 4,096 f
    int*   esrc   = (int*)(cnt + 4096);                   // 500,000 i
    int*   deg    = esrc + 500000;                        // 100,000 i
    int*   off    = deg + 100000;                         // 100,001 i (+pad)
    int*   cursor = off + 100004;                         // 100,000 i
    int*   bsum   = cursor + 100000;                      // 128 i
    int*   boff   = bsum + 128;                           // 128 i

    // ---- CSR build (graph identical every call; ws re-poisoned each call)
    hipMemsetAsync(deg, 0, 100000 * sizeof(int), stream);
    deg_k<<<(EE + 255) / 256, 256, 0, stream>>>(ei, deg);
    scan_part<<<NSB, 256, 0, stream>>>(deg, bsum);
    scan_top<<<1, 128, 0, stream>>>(bsum, boff);
    scan_final<<<NSB, 256, 0, stream>>>(deg, boff, off, cursor);
    bucket_k<<<(EE + 255) / 256, 256, 0, stream>>>(ei, ea, cursor, esrc, eaf);

    // pooled/cnt zero + counts (pooled is written only by layer-3 edge_fused)
    hipMemsetAsync(pooled, 0, (size_t)(BB * HC + BB) * sizeof(float), stream);
    cnt_k<<<(NN + 255) / 256, 256, 0, stream>>>(batch, cnt);

    for (int l = 0; l < 3; l++) {
        const int K = (l == 0) ? 64 : 128;
        const float *Wq, *Wk, *Wv, *Wsk, *bq, *bk, *bv, *bs, *We;
        if (l == 0) {
            Wq = (const float*)d_in[5];  bq = (const float*)d_in[6];
            Wk = (const float*)d_in[7];  bk = (const float*)d_in[8];
            Wv = (const float*)d_in[9];  bv = (const float*)d_in[10];
            We = (const float*)d_in[11];
            Wsk= (const float*)d_in[12]; bs = (const float*)d_in[13];
        } else {
            const int j = l - 1;
            Wq = (const float*)d_in[14] + (size_t)j * HC * HC;  bq = (const float*)d_in[15] + j * HC;
            Wk = (const float*)d_in[16] + (size_t)j * HC * HC;  bk = (const float*)d_in[17] + j * HC;
            Wv = (const float*)d_in[18] + (size_t)j * HC * HC;  bv = (const float*)d_in[19] + j * HC;
            We = (const float*)d_in[20] + (size_t)j * 4 * HC;
            Wsk= (const float*)d_in[21] + (size_t)j * HC * HC;  bs = (const float*)d_in[22] + j * HC;
        }

        prep_w<<<(4 * K * 128 + 255) / 256, 256, 0, stream>>>(Wq, Wk, Wv, Wsk, Wt, K);
        if (K == 64)
            gemm_mfma<2, 1><<<NN / 32, 256, 0, stream>>>(Abf, x, Wt, bq, bk, bv, bs, QSb, KVb);
        else
            gemm_mfma<4, 0><<<NN / 32, 256, 0, stream>>>(Abf, x, Wt, bq, bk, bv, bs, QSb, KVb);
        edge_fused<<<NN / 4, 256, 0, stream>>>(esrc, eaf, We, QSb, KVb, off,
                                               Abf, batch, pooled,
                                               l == 2 ? 1 : 0);
    }

    head_k<<<BB / 4, 256, 0, stream>>>(pooled, cnt, rt,
        (const float*)d_in[23], (const float*)d_in[24], (float*)d_out);
}

// Round 7
// 775.960 us; speedup vs baseline: 1.1593x; 1.1593x over previous
//
#include <hip/hip_runtime.h>
#include <hip/hip_bf16.h>

#define NN 100000
#define EE 500000
#define BB 4096
#define HC 128
#define SCAN_ELEM 1024
#define NSB ((NN + SCAN_ELEM - 1) / SCAN_ELEM)   // 98 blocks

typedef __bf16 bf16_t;
typedef bf16_t bf16x8 __attribute__((ext_vector_type(8)));
typedef float f32x4 __attribute__((ext_vector_type(4)));
typedef float f32x2 __attribute__((ext_vector_type(2)));

__device__ __forceinline__ unsigned short f2bf(float f) {
    unsigned u = __builtin_bit_cast(unsigned, f);
    u += 0x7FFFu + ((u >> 16) & 1u);            // RNE
    return (unsigned short)(u >> 16);
}
__device__ __forceinline__ float bflo(unsigned u) {   // low bf16 -> f32
    return __builtin_bit_cast(float, u << 16);
}
__device__ __forceinline__ float bfhi(unsigned u) {   // high bf16 -> f32
    return __builtin_bit_cast(float, u & 0xFFFF0000u);
}
__device__ __forceinline__ f32x2 unpk2(unsigned u) {  // packed pair -> 2 f32
    return (f32x2){ bflo(u), bfhi(u) };
}

// ---- convert + transpose weights: W[k,n] fp32 -> Wt[p][n*K+k] bf16 ---------
__global__ __launch_bounds__(256) void prep_w(
    const float* __restrict__ Wq, const float* __restrict__ Wk,
    const float* __restrict__ Wv, const float* __restrict__ Ws,
    unsigned short* __restrict__ Wt, int K)
{
    const int g = blockIdx.x * 256 + threadIdx.x;
    const int per = K * 128;
    if (g >= 4 * per) return;
    const int p = g / per, r = g - p * per;
    const int k = r >> 7, n = r & 127;
    const float* W = p == 0 ? Wq : p == 1 ? Wk : p == 2 ? Wv : Ws;
    Wt[(size_t)p * per + (size_t)n * K + k] = f2bf(W[k * 128 + n]);
}

// ---- MFMA GEMM: block = 4 waves = 4 planes, 32-row tile, 128 cols ----------
// ALL outputs packed bf16 (pair per dword), merged planes to cut HBM bytes:
//   QSb[node] = [ Q : 64 dwords | S(skip) : 64 dwords ]   (stride 128)
//   KVb[node] = [ K : 64 dwords | V       : 64 dwords ]   (stride 128)
// F32A=1: A is fp32 (layer-1 x), converted to bf16 fragments in-register.
template<int NKT, int F32A>
__global__ __launch_bounds__(256) void gemm_mfma(
    const unsigned short* __restrict__ Abf,
    const float* __restrict__ xf,
    const unsigned short* __restrict__ Wt,
    const float* __restrict__ bq, const float* __restrict__ bk,
    const float* __restrict__ bv, const float* __restrict__ bs,
    unsigned* __restrict__ QSb, unsigned* __restrict__ KVb)
{
    constexpr int K = NKT * 32;
    const int lane = threadIdx.x & 63;
    const int p = threadIdx.x >> 6;              // wave == plane
    const int m = lane & 15, kq = lane >> 4;
    const int rows0 = blockIdx.x * 32;

    const unsigned short* Wp = Wt + (size_t)p * 128 * K;
    const float* bias = p == 0 ? bq : p == 1 ? bk : p == 2 ? bv : bs;

    bf16x8 a[2][NKT];
#pragma unroll
    for (int mt = 0; mt < 2; mt++)
#pragma unroll
        for (int kt = 0; kt < NKT; kt++) {
            if constexpr (F32A) {
                const float* pr = xf + (size_t)(rows0 + mt * 16 + m) * K + kt * 32 + kq * 8;
                const float4 f0 = *(const float4*)pr;
                const float4 f1 = *(const float4*)(pr + 4);
                union { bf16x8 v; unsigned short u8[8]; } cv;
                cv.u8[0] = f2bf(f0.x); cv.u8[1] = f2bf(f0.y);
                cv.u8[2] = f2bf(f0.z); cv.u8[3] = f2bf(f0.w);
                cv.u8[4] = f2bf(f1.x); cv.u8[5] = f2bf(f1.y);
                cv.u8[6] = f2bf(f1.z); cv.u8[7] = f2bf(f1.w);
                a[mt][kt] = cv.v;
            } else {
                a[mt][kt] = *(const bf16x8*)(Abf + (size_t)(rows0 + mt * 16 + m) * K + kt * 32 + kq * 8);
            }
        }

    f32x4 acc[2][8];
#pragma unroll
    for (int mt = 0; mt < 2; mt++)
#pragma unroll
        for (int nt = 0; nt < 8; nt++)
            acc[mt][nt] = (f32x4){0.f, 0.f, 0.f, 0.f};

#pragma unroll
    for (int nt = 0; nt < 8; nt++) {
#pragma unroll
        for (int kt = 0; kt < NKT; kt++) {
            const bf16x8 b = *(const bf16x8*)(Wp + (size_t)(nt * 16 + m) * K + kt * 32 + kq * 8);
            acc[0][nt] = __builtin_amdgcn_mfma_f32_16x16x32_bf16(a[0][kt], b, acc[0][nt], 0, 0, 0);
            acc[1][nt] = __builtin_amdgcn_mfma_f32_16x16x32_bf16(a[1][kt], b, acc[1][nt], 0, 0, 0);
        }
    }

    unsigned* out = p == 0 ? QSb : p == 1 ? KVb : p == 2 ? (KVb + 64) : (QSb + 64);
#pragma unroll
    for (int nt = 0; nt < 8; nt++) {
        const float bi = bias[nt * 16 + m];
#pragma unroll
        for (int mt = 0; mt < 2; mt++) {
#pragma unroll
            for (int r = 0; r < 4; r++) {
                const float v0 = acc[mt][nt][r] + bi;
                const float v1 = __shfl_xor(v0, 1);
                if (!(m & 1)) {
                    const unsigned pk = (unsigned)f2bf(v0) | ((unsigned)f2bf(v1) << 16);
                    out[(size_t)(rows0 + mt * 16 + kq * 4 + r) * 128 + nt * 8 + (m >> 1)] = pk;
                }
            }
        }
    }
}

// ---- CSR build: degree histogram -> hierarchical scan -> bucket scatter -----
__global__ __launch_bounds__(256) void deg_k(const int* __restrict__ ei, int* __restrict__ deg)
{
    const int e = blockIdx.x * 256 + threadIdx.x;
    if (e < EE) atomicAdd(&deg[ei[EE + e]], 1);
}

__global__ __launch_bounds__(256) void scan_part(const int* __restrict__ deg,
                                                 int* __restrict__ bsum)
{
    __shared__ int red[256];
    const int base = blockIdx.x * SCAN_ELEM + threadIdx.x * 4;
    int s = 0;
#pragma unroll
    for (int j = 0; j < 4; j++) { const int i = base + j; if (i < NN) s += deg[i]; }
    red[threadIdx.x] = s;
    __syncthreads();
    for (int st = 128; st > 0; st >>= 1) {
        if (threadIdx.x < st) red[threadIdx.x] += red[threadIdx.x + st];
        __syncthreads();
    }
    if (threadIdx.x == 0) bsum[blockIdx.x] = red[0];
}

__global__ __launch_bounds__(128) void scan_top(const int* __restrict__ bsum,
                                                int* __restrict__ boff)
{
    __shared__ int buf[128];
    const int v = (threadIdx.x < NSB) ? bsum[threadIdx.x] : 0;
    buf[threadIdx.x] = v;
    __syncthreads();
    for (int s = 1; s < 128; s <<= 1) {
        const int t = (threadIdx.x >= s) ? buf[threadIdx.x - s] : 0;
        __syncthreads();
        buf[threadIdx.x] += t;
        __syncthreads();
    }
    if (threadIdx.x < NSB) boff[threadIdx.x] = buf[threadIdx.x] - v;
}

__global__ __launch_bounds__(256) void scan_final(const int* __restrict__ deg,
                                                  const int* __restrict__ boff,
                                                  int* __restrict__ off,
                                                  int* __restrict__ cursor)
{
    __shared__ int tsum[256];
    const int base = blockIdx.x * SCAN_ELEM + threadIdx.x * 4;
    int vals[4];
    int s = 0;
#pragma unroll
    for (int j = 0; j < 4; j++) {
        const int i = base + j;
        vals[j] = (i < NN) ? deg[i] : 0;
        s += vals[j];
    }
    tsum[threadIdx.x] = s;
    __syncthreads();
    for (int st = 1; st < 256; st <<= 1) {
        const int t = (threadIdx.x >= st) ? tsum[threadIdx.x - st] : 0;
        __syncthreads();
        tsum[threadIdx.x] += t;
        __syncthreads();
    }
    int ex = boff[blockIdx.x] + tsum[threadIdx.x] - s;
#pragma unroll
    for (int j = 0; j < 4; j++) {
        const int i = base + j;
        if (i < NN) { off[i] = ex; cursor[i] = ex; }
        ex += vals[j];
    }
    if (blockIdx.x == NSB - 1 && threadIdx.x == 255)
        off[NN] = boff[blockIdx.x] + tsum[255];
}

// bucket: write src node id AND reordered edge_attr at CSR slot.
__global__ __launch_bounds__(256) void bucket_k(const int* __restrict__ ei,
                                                const float* __restrict__ ea,
                                                int* __restrict__ cursor,
                                                int* __restrict__ esrc,
                                                float4* __restrict__ eaf)
{
    const int e = blockIdx.x * 256 + threadIdx.x;
    if (e < EE) {
        const int d = ei[EE + e];
        const int p = atomicAdd(&cursor[d], 1);
        esrc[p] = ei[e];
        eaf[p] = *(const float4*)(ea + (size_t)e * 4);
    }
}

__global__ __launch_bounds__(256) void cnt_k(const int* __restrict__ batch,
                                             float* __restrict__ cnt)
{
    const int n = blockIdx.x * 256 + threadIdx.x;
    if (n < NN) atomicAdd(&cnt[batch[n]], 1.0f);
}

// ---- Fused edge stage: one wave per dst node, EIGHT edges in flight, ------
// COALESCING-PRESERVING channel split. Lane = slot*8 + c8; slot in [0,8),
// c8 in [0,8). Lane owns 8 channels in EACH ROW HALF:
//   half A: dwords c8*4..+3       (channels c8*8..+7,     head hA = c8>>2)
//   half B: dwords 32+c8*4..+3    (channels 64+c8*8..+7,  head hB = 2+(c8>>2))
// Every dwordx4 load: 8 lanes x 16B contiguous = one full 128B line per row
// (R6's 32B-stride layout doubled sector requests -> BW halved; this keeps
// R5's request count while doubling in-flight edges to 8 x 512B = 4KB/wave).
// Per-half score partials reduce over the c8 quad (xor 1,2); separate
// num/s4/den per half (softmax denominator is per-head).
// Algebra (e = We.a linear): q.(K+e) = q.K + a.(We^T q) folded per half.
// Epilogue: slots 0-3 write half-A pairs, slots 4-7 half-B pairs.
// fuse_pool=0: out = relu(msg/den + skip) -> bf16 Hb (next GEMM input).
// fuse_pool=1: out = msg/den + skip -> atomicAdd into pooled[batch[n]].
__global__ __launch_bounds__(256) void edge_fused(
    const int* __restrict__ esrc, const float4* __restrict__ eaf,
    const float* __restrict__ We,
    const unsigned* __restrict__ QSb, const unsigned* __restrict__ KVb,
    const int* __restrict__ off,
    unsigned short* __restrict__ Hb,
    const int* __restrict__ batch, float* __restrict__ pooled,
    int fuse_pool)
{
    const int lane = threadIdx.x & 63;
    const int slot = lane >> 3;          // edge slot 0..7
    const int c8   = lane & 7;           // channel-quad within each half
    const int n = blockIdx.x * 4 + (threadIdx.x >> 6);

    const int2 be = *(const int2*)(off + n);     // {beg, end} one load
    const int beg = be.x, end = be.y;

    // epilogue channel pair: slots 0-3 -> half A, 4-7 -> half B
    const int ceq = ((slot & 4) << 4) + c8 * 8 + (slot & 3) * 2;

    // issue independent loads early: q row halves + skip pair
    const uint4 qa = *(const uint4*)(QSb + (size_t)n * 128 + c8 * 4);
    const uint4 qb = *(const uint4*)(QSb + (size_t)n * 128 + 32 + c8 * 4);
    const unsigned sku = QSb[(size_t)n * 128 + 64 + ((slot & 4) << 3) + c8 * 4 + (slot & 3)];
    f32x2 qA[4], qB[4];
    qA[0] = unpk2(qa.x); qA[1] = unpk2(qa.y); qA[2] = unpk2(qa.z); qA[3] = unpk2(qa.w);
    qB[0] = unpk2(qb.x); qB[1] = unpk2(qb.y); qB[2] = unpk2(qb.z); qB[3] = unpk2(qb.w);

    // per-lane qe partials per half (reduced jointly with q.K per edge)
    float qepA[4], qepB[4];
#pragma unroll
    for (int d = 0; d < 4; d++) {
        const float4 wa0 = *(const float4*)(We + d * HC + c8 * 8);
        const float4 wa1 = *(const float4*)(We + d * HC + c8 * 8 + 4);
        qepA[d] = wa0.x * qA[0].x + wa0.y * qA[0].y + wa0.z * qA[1].x + wa0.w * qA[1].y
                + wa1.x * qA[2].x + wa1.y * qA[2].y + wa1.z * qA[3].x + wa1.w * qA[3].y;
        const float4 wb0 = *(const float4*)(We + d * HC + 64 + c8 * 8);
        const float4 wb1 = *(const float4*)(We + d * HC + 64 + c8 * 8 + 4);
        qepB[d] = wb0.x * qB[0].x + wb0.y * qB[0].y + wb0.z * qB[1].x + wb0.w * qB[1].y
                + wb1.x * qB[2].x + wb1.y * qB[2].y + wb1.z * qB[3].x + wb1.w * qB[3].y;
    }

    f32x2 numA[4] = {(f32x2){0.f,0.f},(f32x2){0.f,0.f},(f32x2){0.f,0.f},(f32x2){0.f,0.f}};
    f32x2 numB[4] = {(f32x2){0.f,0.f},(f32x2){0.f,0.f},(f32x2){0.f,0.f},(f32x2){0.f,0.f}};
    f32x4 s4A = (f32x4){0.f,0.f,0.f,0.f}, s4B = (f32x4){0.f,0.f,0.f,0.f};
    float denA = 0.f, denB = 0.f;

    if (beg < end) {
        const int e1 = end - 1;
        int p0 = beg + slot; if (p0 > e1) p0 = e1;
        int src = esrc[p0];
        float4 a4 = eaf[p0];
        for (int base = beg; base < end; base += 8) {
            const unsigned* kv = KVb + (size_t)src * 128 + c8 * 4;
            const uint4 ka = *(const uint4*)kv;          // K half A (line 0)
            const uint4 kb = *(const uint4*)(kv + 32);   // K half B (line 1)
            const uint4 va = *(const uint4*)(kv + 64);   // V half A
            const uint4 vb = *(const uint4*)(kv + 96);   // V half B
            const float4 ac = a4;
            const bool act = (base + slot) < end;
            if (base + 8 < end) {                  // 1-ahead prefetch
                int pn = base + 8 + slot; if (pn > e1) pn = e1;
                src = esrc[pn]; a4 = eaf[pn];
            }
            f32x2 tA = qA[0] * unpk2(ka.x);
            tA += qA[1] * unpk2(ka.y);
            tA += qA[2] * unpk2(ka.z);
            tA += qA[3] * unpk2(ka.w);
            f32x2 tB = qB[0] * unpk2(kb.x);
            tB += qB[1] * unpk2(kb.y);
            tB += qB[2] * unpk2(kb.z);
            tB += qB[3] * unpk2(kb.w);
            float totA = tA.x + tA.y
                       + ac.x * qepA[0] + ac.y * qepA[1] + ac.z * qepA[2] + ac.w * qepA[3];
            float totB = tB.x + tB.y
                       + ac.x * qepB[0] + ac.y * qepB[1] + ac.z * qepB[2] + ac.w * qepB[3];
            totA += __shfl_xor(totA, 1); totB += __shfl_xor(totB, 1);
            totA += __shfl_xor(totA, 2); totB += __shfl_xor(totB, 2);
            float alA = __expf(totA * 0.17677669529663687f);   // 1/sqrt(32)
            float alB = __expf(totB * 0.17677669529663687f);
            if (!act) { alA = 0.f; alB = 0.f; }
            numA[0] += unpk2(va.x) * alA;
            numA[1] += unpk2(va.y) * alA;
            numA[2] += unpk2(va.z) * alA;
            numA[3] += unpk2(va.w) * alA;
            numB[0] += unpk2(vb.x) * alB;
            numB[1] += unpk2(vb.y) * alB;
            numB[2] += unpk2(vb.z) * alB;
            numB[3] += unpk2(vb.w) * alB;
            s4A.x += ac.x * alA; s4A.y += ac.y * alA;
            s4A.z += ac.z * alA; s4A.w += ac.w * alA;
            s4B.x += ac.x * alB; s4B.y += ac.y * alB;
            s4B.z += ac.z * alB; s4B.w += ac.w * alB;
            denA += alA; denB += alB;
        }
    }

    // cross-slot combine (once per node): slot bits are lane bits 3,4,5
#pragma unroll
    for (int st = 8; st < 64; st <<= 1) {
#pragma unroll
        for (int j = 0; j < 4; j++) {
            numA[j].x += __shfl_xor(numA[j].x, st);
            numA[j].y += __shfl_xor(numA[j].y, st);
            numB[j].x += __shfl_xor(numB[j].x, st);
            numB[j].y += __shfl_xor(numB[j].y, st);
        }
        s4A.x += __shfl_xor(s4A.x, st); s4A.y += __shfl_xor(s4A.y, st);
        s4A.z += __shfl_xor(s4A.z, st); s4A.w += __shfl_xor(s4A.w, st);
        s4B.x += __shfl_xor(s4B.x, st); s4B.y += __shfl_xor(s4B.y, st);
        s4B.z += __shfl_xor(s4B.z, st); s4B.w += __shfl_xor(s4B.w, st);
        denA += __shfl_xor(denA, st);
        denB += __shfl_xor(denB, st);
    }

    // select my half (slot<4 -> A, else B); static-index num selection
    f32x2 mynum;
    switch (slot) {
        case 0: mynum = numA[0]; break;
        case 1: mynum = numA[1]; break;
        case 2: mynum = numA[2]; break;
        case 3: mynum = numA[3]; break;
        case 4: mynum = numB[0]; break;
        case 5: mynum = numB[1]; break;
        case 6: mynum = numB[2]; break;
        default: mynum = numB[3]; break;
    }
    const bool hB = slot >= 4;
    const float inv = 1.f / ((hB ? denB : denA) + 1e-16f);
    const f32x4 s4 = hB ? s4B : s4A;

    // edge-attr contribution for my 2 channels: We . s4(half)
    float ev0 = 0.f, ev1 = 0.f;
#pragma unroll
    for (int d = 0; d < 4; d++) {
        const float2 wd = *(const float2*)(We + d * HC + ceq);
        const float sd = d == 0 ? s4.x : d == 1 ? s4.y : d == 2 ? s4.z : s4.w;
        ev0 += sd * wd.x;
        ev1 += sd * wd.y;
    }
    const float o0 = (mynum.x + ev0) * inv + bflo(sku);
    const float o1 = (mynum.y + ev1) * inv + bfhi(sku);

    if (!fuse_pool) {
        const float r0 = fmaxf(o0, 0.f), r1 = fmaxf(o1, 0.f);
        const unsigned pk = (unsigned)f2bf(r0) | ((unsigned)f2bf(r1) << 16);
        *(unsigned*)(Hb + (size_t)n * HC + ceq) = pk;   // 64 lanes = 256B row
    } else {
        const int b = batch[n];
        atomicAdd(pooled + (size_t)b * HC + ceq,     o0);
        atomicAdd(pooled + (size_t)b * HC + ceq + 1, o1);
    }
}

__global__ __launch_bounds__(256) void head_k(
    const float* __restrict__ pooled, const float* __restrict__ cnt,
    const int* __restrict__ rt, const float* __restrict__ hW,
    const float* __restrict__ hb, float* __restrict__ out)
{
    const int lane = threadIdx.x & 63;
    const int b = blockIdx.x * 4 + (threadIdx.x >> 6);
    if (b >= BB) return;
    const int t = rt[b];
    const int c = lane * 2;
    const float2 p2 = *(const float2*)(pooled + (size_t)b * HC + c);
    const float2 w2 = *(const float2*)(hW + (size_t)t * HC + c);
    float part = p2.x * w2.x + p2.y * w2.y;
    part += __shfl_xor(part, 1);
    part += __shfl_xor(part, 2);
    part += __shfl_xor(part, 4);
    part += __shfl_xor(part, 8);
    part += __shfl_xor(part, 16);
    part += __shfl_xor(part, 32);
    if (lane == 0) out[b] = part / fmaxf(cnt[b], 1.0f) + hb[t];
}

extern "C" void kernel_launch(void* const* d_in, const int* in_sizes, int n_in,
                              void* d_out, int out_size, void* d_ws, size_t ws_size,
                              hipStream_t stream) {
    const float* x      = (const float*)d_in[0];
    const int*   ei     = (const int*)d_in[1];
    const float* ea     = (const float*)d_in[2];
    const int*   batch  = (const int*)d_in[3];
    const int*   rt     = (const int*)d_in[4];

    // workspace layout — big 16B-aligned arrays first; ~141 MB total
    unsigned* QSb = (unsigned*)d_ws;                      // 12,800,000 u32 (Q|S bf16)
    unsigned* KVb = QSb + 12800000;                       // 12,800,000 u32 (K|V bf16)
    unsigned short* Abf = (unsigned short*)(KVb + 12800000); // 12,800,000 us (h plane)
    float4* eaf   = (float4*)(Abf + 12800000);            // 500,000 float4
    unsigned short* Wt = (unsigned short*)(eaf + 500000); // 65,536 us
    float* pooled = (float*)(Wt + 65536);                 // 524,288 f
    float* cnt    = pooled + 524288;                      // 4,096 f
    int*   esrc   = (int*)(cnt + 4096);                   // 500,000 i
    int*   deg    = esrc + 500000;                        // 100,000 i
    int*   off    = deg + 100000;                         // 100,001 i (+pad)
    int*   cursor = off + 100004;                         // 100,000 i
    int*   bsum   = cursor + 100000;                      // 128 i
    int*   boff   = bsum + 128;                           // 128 i

    // ---- CSR build (graph identical every call; ws re-poisoned each call)
    hipMemsetAsync(deg, 0, 100000 * sizeof(int), stream);
    deg_k<<<(EE + 255) / 256, 256, 0, stream>>>(ei, deg);
    scan_part<<<NSB, 256, 0, stream>>>(deg, bsum);
    scan_top<<<1, 128, 0, stream>>>(bsum, boff);
    scan_final<<<NSB, 256, 0, stream>>>(deg, boff, off, cursor);
    bucket_k<<<(EE + 255) / 256, 256, 0, stream>>>(ei, ea, cursor, esrc, eaf);

    // pooled/cnt zero + counts (pooled is written only by layer-3 edge_fused)
    hipMemsetAsync(pooled, 0, (size_t)(BB * HC + BB) * sizeof(float), stream);
    cnt_k<<<(NN + 255) / 256, 256, 0, stream>>>(batch, cnt);

    for (int l = 0; l < 3; l++) {
        const int K = (l == 0) ? 64 : 128;
        const float *Wq, *Wk, *Wv, *Wsk, *bq, *bk, *bv, *bs, *We;
        if (l == 0) {
            Wq = (const float*)d_in[5];  bq = (const float*)d_in[6];
            Wk = (const float*)d_in[7];  bk = (const float*)d_in[8];
            Wv = (const float*)d_in[9];  bv = (const float*)d_in[10];
            We = (const float*)d_in[11];
            Wsk= (const float*)d_in[12]; bs = (const float*)d_in[13];
        } else {
            const int j = l - 1;
            Wq = (const float*)d_in[14] + (size_t)j * HC * HC;  bq = (const float*)d_in[15] + j * HC;
            Wk = (const float*)d_in[16] + (size_t)j * HC * HC;  bk = (const float*)d_in[17] + j * HC;
            Wv = (const float*)d_in[18] + (size_t)j * HC * HC;  bv = (const float*)d_in[19] + j * HC;
            We = (const float*)d_in[20] + (size_t)j * 4 * HC;
            Wsk= (const float*)d_in[21] + (size_t)j * HC * HC;  bs = (const float*)d_in[22] + j * HC;
        }

        prep_w<<<(4 * K * 128 + 255) / 256, 256, 0, stream>>>(Wq, Wk, Wv, Wsk, Wt, K);
        if (K == 64)
            gemm_mfma<2, 1><<<NN / 32, 256, 0, stream>>>(Abf, x, Wt, bq, bk, bv, bs, QSb, KVb);
        else
            gemm_mfma<4, 0><<<NN / 32, 256, 0, stream>>>(Abf, x, Wt, bq, bk, bv, bs, QSb, KVb);
        edge_fused<<<NN / 4, 256, 0, stream>>>(esrc, eaf, We, QSb, KVb, off,
                                               Abf, batch, pooled,
                                               l == 2 ? 1 : 0);
    }

    head_k<<<BB / 4, 256, 0, stream>>>(pooled, cnt, rt,
        (const float*)d_in[23], (const float*)d_in[24], (float*)d_out);
}

// Round 8
// 693.396 us; speedup vs baseline: 1.2973x; 1.1191x over previous
//
#include <hip/hip_runtime.h>
#include <hip/hip_bf16.h>

#define NN 100000
#define EE 500000
#define BB 4096
#define HC 128
#define SCAN_ELEM 1024
#define NSB ((NN + SCAN_ELEM - 1) / SCAN_ELEM)   // 98 blocks

typedef __bf16 bf16_t;
typedef bf16_t bf16x8 __attribute__((ext_vector_type(8)));
typedef float f32x4 __attribute__((ext_vector_type(4)));
typedef float f32x2 __attribute__((ext_vector_type(2)));

__device__ __forceinline__ unsigned short f2bf(float f) {
    unsigned u = __builtin_bit_cast(unsigned, f);
    u += 0x7FFFu + ((u >> 16) & 1u);            // RNE
    return (unsigned short)(u >> 16);
}
__device__ __forceinline__ float bflo(unsigned u) {   // low bf16 -> f32
    return __builtin_bit_cast(float, u << 16);
}
__device__ __forceinline__ float bfhi(unsigned u) {   // high bf16 -> f32
    return __builtin_bit_cast(float, u & 0xFFFF0000u);
}
__device__ __forceinline__ f32x2 unpk2(unsigned u) {  // packed pair -> 2 f32
    return (f32x2){ bflo(u), bfhi(u) };
}

// ---- convert + transpose weights: W[k,n] fp32 -> Wt[p][n*K+k] bf16 ---------
__global__ __launch_bounds__(256) void prep_w(
    const float* __restrict__ Wq, const float* __restrict__ Wk,
    const float* __restrict__ Wv, const float* __restrict__ Ws,
    unsigned short* __restrict__ Wt, int K)
{
    const int g = blockIdx.x * 256 + threadIdx.x;
    const int per = K * 128;
    if (g >= 4 * per) return;
    const int p = g / per, r = g - p * per;
    const int k = r >> 7, n = r & 127;
    const float* W = p == 0 ? Wq : p == 1 ? Wk : p == 2 ? Wv : Ws;
    Wt[(size_t)p * per + (size_t)n * K + k] = f2bf(W[k * 128 + n]);
}

// ---- MFMA GEMM: block = 4 waves = 4 planes, 32-row tile, 128 cols ----------
// ALL outputs packed bf16 (pair per dword), merged planes to cut HBM bytes:
//   QSb[node] = [ Q : 64 dwords | S(skip) : 64 dwords ]   (stride 128)
//   KVb[node] = [ K : 64 dwords | V       : 64 dwords ]   (stride 128)
// F32A=1: A is fp32 (layer-1 x), converted to bf16 fragments in-register.
template<int NKT, int F32A>
__global__ __launch_bounds__(256) void gemm_mfma(
    const unsigned short* __restrict__ Abf,
    const float* __restrict__ xf,
    const unsigned short* __restrict__ Wt,
    const float* __restrict__ bq, const float* __restrict__ bk,
    const float* __restrict__ bv, const float* __restrict__ bs,
    unsigned* __restrict__ QSb, unsigned* __restrict__ KVb)
{
    constexpr int K = NKT * 32;
    const int lane = threadIdx.x & 63;
    const int p = threadIdx.x >> 6;              // wave == plane
    const int m = lane & 15, kq = lane >> 4;
    const int rows0 = blockIdx.x * 32;

    const unsigned short* Wp = Wt + (size_t)p * 128 * K;
    const float* bias = p == 0 ? bq : p == 1 ? bk : p == 2 ? bv : bs;

    bf16x8 a[2][NKT];
#pragma unroll
    for (int mt = 0; mt < 2; mt++)
#pragma unroll
        for (int kt = 0; kt < NKT; kt++) {
            if constexpr (F32A) {
                const float* pr = xf + (size_t)(rows0 + mt * 16 + m) * K + kt * 32 + kq * 8;
                const float4 f0 = *(const float4*)pr;
                const float4 f1 = *(const float4*)(pr + 4);
                union { bf16x8 v; unsigned short u8[8]; } cv;
                cv.u8[0] = f2bf(f0.x); cv.u8[1] = f2bf(f0.y);
                cv.u8[2] = f2bf(f0.z); cv.u8[3] = f2bf(f0.w);
                cv.u8[4] = f2bf(f1.x); cv.u8[5] = f2bf(f1.y);
                cv.u8[6] = f2bf(f1.z); cv.u8[7] = f2bf(f1.w);
                a[mt][kt] = cv.v;
            } else {
                a[mt][kt] = *(const bf16x8*)(Abf + (size_t)(rows0 + mt * 16 + m) * K + kt * 32 + kq * 8);
            }
        }

    f32x4 acc[2][8];
#pragma unroll
    for (int mt = 0; mt < 2; mt++)
#pragma unroll
        for (int nt = 0; nt < 8; nt++)
            acc[mt][nt] = (f32x4){0.f, 0.f, 0.f, 0.f};

#pragma unroll
    for (int nt = 0; nt < 8; nt++) {
#pragma unroll
        for (int kt = 0; kt < NKT; kt++) {
            const bf16x8 b = *(const bf16x8*)(Wp + (size_t)(nt * 16 + m) * K + kt * 32 + kq * 8);
            acc[0][nt] = __builtin_amdgcn_mfma_f32_16x16x32_bf16(a[0][kt], b, acc[0][nt], 0, 0, 0);
            acc[1][nt] = __builtin_amdgcn_mfma_f32_16x16x32_bf16(a[1][kt], b, acc[1][nt], 0, 0, 0);
        }
    }

    unsigned* out = p == 0 ? QSb : p == 1 ? KVb : p == 2 ? (KVb + 64) : (QSb + 64);
#pragma unroll
    for (int nt = 0; nt < 8; nt++) {
        const float bi = bias[nt * 16 + m];
#pragma unroll
        for (int mt = 0; mt < 2; mt++) {
#pragma unroll
            for (int r = 0; r < 4; r++) {
                const float v0 = acc[mt][nt][r] + bi;
                const float v1 = __shfl_xor(v0, 1);
                if (!(m & 1)) {
                    const unsigned pk = (unsigned)f2bf(v0) | ((unsigned)f2bf(v1) << 16);
                    out[(size_t)(rows0 + mt * 16 + kq * 4 + r) * 128 + nt * 8 + (m >> 1)] = pk;
                }
            }
        }
    }
}

// ---- CSR build: degree histogram -> hierarchical scan -> bucket scatter -----
__global__ __launch_bounds__(256) void deg_k(const int* __restrict__ ei, int* __restrict__ deg)
{
    const int e = blockIdx.x * 256 + threadIdx.x;
    if (e < EE) atomicAdd(&deg[ei[EE + e]], 1);
}

__global__ __launch_bounds__(256) void scan_part(const int* __restrict__ deg,
                                                 int* __restrict__ bsum)
{
    __shared__ int red[256];
    const int base = blockIdx.x * SCAN_ELEM + threadIdx.x * 4;
    int s = 0;
#pragma unroll
    for (int j = 0; j < 4; j++) { const int i = base + j; if (i < NN) s += deg[i]; }
    red[threadIdx.x] = s;
    __syncthreads();
    for (int st = 128; st > 0; st >>= 1) {
        if (threadIdx.x < st) red[threadIdx.x] += red[threadIdx.x + st];
        __syncthreads();
    }
    if (threadIdx.x == 0) bsum[blockIdx.x] = red[0];
}

__global__ __launch_bounds__(128) void scan_top(const int* __restrict__ bsum,
                                                int* __restrict__ boff)
{
    __shared__ int buf[128];
    const int v = (threadIdx.x < NSB) ? bsum[threadIdx.x] : 0;
    buf[threadIdx.x] = v;
    __syncthreads();
    for (int s = 1; s < 128; s <<= 1) {
        const int t = (threadIdx.x >= s) ? buf[threadIdx.x - s] : 0;
        __syncthreads();
        buf[threadIdx.x] += t;
        __syncthreads();
    }
    if (threadIdx.x < NSB) boff[threadIdx.x] = buf[threadIdx.x] - v;
}

// scan_final also folds the per-graph node count (cnt_k) -- same node domain,
// saves one dispatch + one pass over batch[]. cnt must be zeroed BEFORE this.
__global__ __launch_bounds__(256) void scan_final(const int* __restrict__ deg,
                                                  const int* __restrict__ boff,
                                                  int* __restrict__ off,
                                                  int* __restrict__ cursor,
                                                  const int* __restrict__ batch,
                                                  float* __restrict__ cnt)
{
    __shared__ int tsum[256];
    const int base = blockIdx.x * SCAN_ELEM + threadIdx.x * 4;
    int vals[4];
    int s = 0;
#pragma unroll
    for (int j = 0; j < 4; j++) {
        const int i = base + j;
        vals[j] = (i < NN) ? deg[i] : 0;
        s += vals[j];
    }
    tsum[threadIdx.x] = s;
    __syncthreads();
    for (int st = 1; st < 256; st <<= 1) {
        const int t = (threadIdx.x >= st) ? tsum[threadIdx.x - st] : 0;
        __syncthreads();
        tsum[threadIdx.x] += t;
        __syncthreads();
    }
    int ex = boff[blockIdx.x] + tsum[threadIdx.x] - s;
#pragma unroll
    for (int j = 0; j < 4; j++) {
        const int i = base + j;
        if (i < NN) {
            off[i] = ex; cursor[i] = ex;
            atomicAdd(&cnt[batch[i]], 1.0f);
        }
        ex += vals[j];
    }
    if (blockIdx.x == NSB - 1 && threadIdx.x == 255)
        off[NN] = boff[blockIdx.x] + tsum[255];
}

// bucket: write src node id AND reordered edge_attr at CSR slot.
__global__ __launch_bounds__(256) void bucket_k(const int* __restrict__ ei,
                                                const float* __restrict__ ea,
                                                int* __restrict__ cursor,
                                                int* __restrict__ esrc,
                                                float4* __restrict__ eaf)
{
    const int e = blockIdx.x * 256 + threadIdx.x;
    if (e < EE) {
        const int d = ei[EE + e];
        const int p = atomicAdd(&cursor[d], 1);
        esrc[p] = ei[e];
        eaf[p] = *(const float4*)(ea + (size_t)e * 4);
    }
}

// ---- Fused edge stage: one wave per TWO nodes, processed IN PARALLEL. ------
// Lane = slot*16 + c8 (R5 layout, measured-best): slot in [0,4) edge slot,
// c8 in [0,16) owns 8 channels (one dwordx4 of packed bf16; V at +64 dwords).
// Each wave handles nodes nA = 2*w and nB = nA+1 concurrently: two
// independent gather->score->accumulate chains interleaved -> 2x in-flight
// bytes (~2KB/wave) at UNCHANGED request shape/lane efficiency (R6/R7 showed
// widening the slot axis taxes coalescing or VALU; the node axis doesn't).
// Per-node guards (dA,dB) are wave-uniform -> no divergence.
// Algebra (e = We.a linear): q.(K+e) = q.K + a.(We^T q); per-lane qep folds
// into the per-edge shuffle reduce; sum(alpha*(V+e)) = sum(alpha*V) +
// We.(sum(alpha*a)) with running s4.
// fuse_pool=0: out = relu(msg/den + skip) -> bf16 Hb (next GEMM input).
// fuse_pool=1: out = msg/den + skip -> atomicAdd into pooled[batch[n]].
__global__ __launch_bounds__(256) void edge_fused(
    const int* __restrict__ esrc, const float4* __restrict__ eaf,
    const float* __restrict__ We,
    const unsigned* __restrict__ QSb, const unsigned* __restrict__ KVb,
    const int* __restrict__ off,
    unsigned short* __restrict__ Hb,
    const int* __restrict__ batch, float* __restrict__ pooled,
    int fuse_pool)
{
    const int lane = threadIdx.x & 63;
    const int slot = lane >> 4;          // edge slot 0..3
    const int c8   = lane & 15;          // channel group: channels c8*8 .. +7
    const int cb   = c8 * 8;
    const int ceq  = cb + slot * 2;      // epilogue channel pair
    const int nA = (blockIdx.x * 4 + (threadIdx.x >> 6)) * 2;
    const int nB = nA + 1;

    // off[nA], off[nA+1](=endA=begB), off[nA+2]; nA even -> 8B-aligned int2
    const int2 beA = *(const int2*)(off + nA);
    const int begA = beA.x, endA = beA.y;
    const int begB = endA, endB = off[nB + 1];
    const int dA = endA - begA, dB = endB - begB;

    // issue independent loads early: q rows + bf16 skip pairs
    const uint4 qvA = *(const uint4*)(QSb + (size_t)nA * 128 + c8 * 4);
    const uint4 qvB = *(const uint4*)(QSb + (size_t)nB * 128 + c8 * 4);
    const unsigned skA = QSb[(size_t)nA * 128 + 64 + c8 * 4 + slot];
    const unsigned skB = QSb[(size_t)nB * 128 + 64 + c8 * 4 + slot];
    f32x2 qA[4], qB[4];
    qA[0] = unpk2(qvA.x); qA[1] = unpk2(qvA.y);
    qA[2] = unpk2(qvA.z); qA[3] = unpk2(qvA.w);
    qB[0] = unpk2(qvB.x); qB[1] = unpk2(qvB.y);
    qB[2] = unpk2(qvB.z); qB[3] = unpk2(qvB.w);

    // per-lane qe partials over my 8 channels (We rows loaded once, used 2x)
    float qepA[4], qepB[4];
#pragma unroll
    for (int d = 0; d < 4; d++) {
        const float4 wa = *(const float4*)(We + d * HC + cb);
        const float4 wb = *(const float4*)(We + d * HC + cb + 4);
        qepA[d] = wa.x * qA[0].x + wa.y * qA[0].y + wa.z * qA[1].x + wa.w * qA[1].y
                + wb.x * qA[2].x + wb.y * qA[2].y + wb.z * qA[3].x + wb.w * qA[3].y;
        qepB[d] = wa.x * qB[0].x + wa.y * qB[0].y + wa.z * qB[1].x + wa.w * qB[1].y
                + wb.x * qB[2].x + wb.y * qB[2].y + wb.z * qB[3].x + wb.w * qB[3].y;
    }

    f32x2 numA[4] = {(f32x2){0.f,0.f},(f32x2){0.f,0.f},(f32x2){0.f,0.f},(f32x2){0.f,0.f}};
    f32x2 numB[4] = {(f32x2){0.f,0.f},(f32x2){0.f,0.f},(f32x2){0.f,0.f},(f32x2){0.f,0.f}};
    f32x4 s4A = (f32x4){0.f,0.f,0.f,0.f}, s4B = (f32x4){0.f,0.f,0.f,0.f};
    float denA = 0.f, denB = 0.f;

    int srcA = 0, srcB = 0;
    float4 a4A = make_float4(0.f,0.f,0.f,0.f), a4B = make_float4(0.f,0.f,0.f,0.f);
    if (dA > 0) { const int p = begA + (slot < dA ? slot : dA - 1); srcA = esrc[p]; a4A = eaf[p]; }
    if (dB > 0) { const int p = begB + (slot < dB ? slot : dB - 1); srcB = esrc[p]; a4B = eaf[p]; }

    const int dmax = dA > dB ? dA : dB;
    for (int o = 0; o < dmax; o += 4) {
        const bool anyA = o < dA, anyB = o < dB;     // wave-uniform
        uint4 kuA, vuA, kuB, vuB;
        float4 acA, acB;
        if (anyA) {                                   // issue both gathers first
            const unsigned* kv = KVb + (size_t)srcA * 128 + c8 * 4;
            kuA = *(const uint4*)kv; vuA = *(const uint4*)(kv + 64);
        }
        if (anyB) {
            const unsigned* kv = KVb + (size_t)srcB * 128 + c8 * 4;
            kuB = *(const uint4*)kv; vuB = *(const uint4*)(kv + 64);
        }
        if (anyA) {
            acA = a4A;
            if (o + 4 < dA) {                        // 1-ahead prefetch
                const int t = o + 4 + slot;
                const int p = begA + (t < dA ? t : dA - 1);
                srcA = esrc[p]; a4A = eaf[p];
            }
        }
        if (anyB) {
            acB = a4B;
            if (o + 4 < dB) {
                const int t = o + 4 + slot;
                const int p = begB + (t < dB ? t : dB - 1);
                srcB = esrc[p]; a4B = eaf[p];
            }
        }
        if (anyA) {
            f32x2 t2 = qA[0] * unpk2(kuA.x);
            t2 += qA[1] * unpk2(kuA.y);
            t2 += qA[2] * unpk2(kuA.z);
            t2 += qA[3] * unpk2(kuA.w);
            float tot = t2.x + t2.y
                      + acA.x * qepA[0] + acA.y * qepA[1] + acA.z * qepA[2] + acA.w * qepA[3];
            tot += __shfl_xor(tot, 1);
            tot += __shfl_xor(tot, 2);
            float al = __expf(tot * 0.17677669529663687f);   // 1/sqrt(32)
            if ((o + slot) >= dA) al = 0.f;
            numA[0] += unpk2(vuA.x) * al;
            numA[1] += unpk2(vuA.y) * al;
            numA[2] += unpk2(vuA.z) * al;
            numA[3] += unpk2(vuA.w) * al;
            s4A.x += acA.x * al; s4A.y += acA.y * al;
            s4A.z += acA.z * al; s4A.w += acA.w * al;
            denA += al;
        }
        if (anyB) {
            f32x2 t2 = qB[0] * unpk2(kuB.x);
            t2 += qB[1] * unpk2(kuB.y);
            t2 += qB[2] * unpk2(kuB.z);
            t2 += qB[3] * unpk2(kuB.w);
            float tot = t2.x + t2.y
                      + acB.x * qepB[0] + acB.y * qepB[1] + acB.z * qepB[2] + acB.w * qepB[3];
            tot += __shfl_xor(tot, 1);
            tot += __shfl_xor(tot, 2);
            float al = __expf(tot * 0.17677669529663687f);
            if ((o + slot) >= dB) al = 0.f;
            numB[0] += unpk2(vuB.x) * al;
            numB[1] += unpk2(vuB.y) * al;
            numB[2] += unpk2(vuB.z) * al;
            numB[3] += unpk2(vuB.w) * al;
            s4B.x += acB.x * al; s4B.y += acB.y * al;
            s4B.z += acB.z * al; s4B.w += acB.w * al;
            denB += al;
        }
    }

    // cross-slot combine (once per node pair)
#pragma unroll
    for (int st = 16; st < 64; st <<= 1) {
#pragma unroll
        for (int j = 0; j < 4; j++) {
            numA[j].x += __shfl_xor(numA[j].x, st);
            numA[j].y += __shfl_xor(numA[j].y, st);
            numB[j].x += __shfl_xor(numB[j].x, st);
            numB[j].y += __shfl_xor(numB[j].y, st);
        }
        s4A.x += __shfl_xor(s4A.x, st); s4A.y += __shfl_xor(s4A.y, st);
        s4A.z += __shfl_xor(s4A.z, st); s4A.w += __shfl_xor(s4A.w, st);
        s4B.x += __shfl_xor(s4B.x, st); s4B.y += __shfl_xor(s4B.y, st);
        s4B.z += __shfl_xor(s4B.z, st); s4B.w += __shfl_xor(s4B.w, st);
        denA += __shfl_xor(denA, st);
        denB += __shfl_xor(denB, st);
    }
    const float invA = 1.f / (denA + 1e-16f);
    const float invB = 1.f / (denB + 1e-16f);

    // my channel pair (static-index selection)
    f32x2 mynA = slot == 0 ? numA[0] : slot == 1 ? numA[1]
               : slot == 2 ? numA[2] : numA[3];
    f32x2 mynB = slot == 0 ? numB[0] : slot == 1 ? numB[1]
               : slot == 2 ? numB[2] : numB[3];
    // edge-attr contribution for my 2 channels: We . s4 (We pair loaded once)
    float evA0 = 0.f, evA1 = 0.f, evB0 = 0.f, evB1 = 0.f;
#pragma unroll
    for (int d = 0; d < 4; d++) {
        const float2 wd = *(const float2*)(We + d * HC + ceq);
        const float sdA = d == 0 ? s4A.x : d == 1 ? s4A.y : d == 2 ? s4A.z : s4A.w;
        const float sdB = d == 0 ? s4B.x : d == 1 ? s4B.y : d == 2 ? s4B.z : s4B.w;
        evA0 += sdA * wd.x; evA1 += sdA * wd.y;
        evB0 += sdB * wd.x; evB1 += sdB * wd.y;
    }
    const float oA0 = (mynA.x + evA0) * invA + bflo(skA);
    const float oA1 = (mynA.y + evA1) * invA + bfhi(skA);
    const float oB0 = (mynB.x + evB0) * invB + bflo(skB);
    const float oB1 = (mynB.y + evB1) * invB + bfhi(skB);

    if (!fuse_pool) {
        const unsigned pkA = (unsigned)f2bf(fmaxf(oA0, 0.f)) | ((unsigned)f2bf(fmaxf(oA1, 0.f)) << 16);
        const unsigned pkB = (unsigned)f2bf(fmaxf(oB0, 0.f)) | ((unsigned)f2bf(fmaxf(oB1, 0.f)) << 16);
        *(unsigned*)(Hb + (size_t)nA * HC + ceq) = pkA;   // 64 lanes = 256B row
        *(unsigned*)(Hb + (size_t)nB * HC + ceq) = pkB;
    } else {
        const int bA = batch[nA], bB = batch[nB];
        atomicAdd(pooled + (size_t)bA * HC + ceq,     oA0);
        atomicAdd(pooled + (size_t)bA * HC + ceq + 1, oA1);
        atomicAdd(pooled + (size_t)bB * HC + ceq,     oB0);
        atomicAdd(pooled + (size_t)bB * HC + ceq + 1, oB1);
    }
}

__global__ __launch_bounds__(256) void head_k(
    const float* __restrict__ pooled, const float* __restrict__ cnt,
    const int* __restrict__ rt, const float* __restrict__ hW,
    const float* __restrict__ hb, float* __restrict__ out)
{
    const int lane = threadIdx.x & 63;
    const int b = blockIdx.x * 4 + (threadIdx.x >> 6);
    if (b >= BB) return;
    const int t = rt[b];
    const int c = lane * 2;
    const float2 p2 = *(const float2*)(pooled + (size_t)b * HC + c);
    const float2 w2 = *(const float2*)(hW + (size_t)t * HC + c);
    float part = p2.x * w2.x + p2.y * w2.y;
    part += __shfl_xor(part, 1);
    part += __shfl_xor(part, 2);
    part += __shfl_xor(part, 4);
    part += __shfl_xor(part, 8);
    part += __shfl_xor(part, 16);
    part += __shfl_xor(part, 32);
    if (lane == 0) out[b] = part / fmaxf(cnt[b], 1.0f) + hb[t];
}

extern "C" void kernel_launch(void* const* d_in, const int* in_sizes, int n_in,
                              void* d_out, int out_size, void* d_ws, size_t ws_size,
                              hipStream_t stream) {
    const float* x      = (const float*)d_in[0];
    const int*   ei     = (const int*)d_in[1];
    const float* ea     = (const float*)d_in[2];
    const int*   batch  = (const int*)d_in[3];
    const int*   rt     = (const int*)d_in[4];

    // workspace layout — big 16B-aligned arrays first; ~141 MB total
    unsigned* QSb = (unsigned*)d_ws;                      // 12,800,000 u32 (Q|S bf16)
    unsigned* KVb = QSb + 12800000;                       // 12,800,000 u32 (K|V bf16)
    unsigned short* Abf = (unsigned short*)(KVb + 12800000); // 12,800,000 us (h plane)
    float4* eaf   = (float4*)(Abf + 12800000);            // 500,000 float4
    unsigned short* Wt = (unsigned short*)(eaf + 500000); // 65,536 us
    float* pooled = (float*)(Wt + 65536);                 // 524,288 f
    float* cnt    = pooled + 524288;                      // 4,096 f
    int*   esrc   = (int*)(cnt + 4096);                   // 500,000 i
    int*   deg    = esrc + 500000;                        // 100,000 i
    int*   off    = deg + 100000;                         // 100,001 i (+pad)
    int*   cursor = off + 100004;                         // 100,000 i
    int*   bsum   = cursor + 100000;                      // 128 i
    int*   boff   = bsum + 128;                           // 128 i

    // ---- CSR build (graph identical every call; ws re-poisoned each call)
    hipMemsetAsync(deg, 0, 100000 * sizeof(int), stream);
    // pooled/cnt zero must precede scan_final (cnt fold)
    hipMemsetAsync(pooled, 0, (size_t)(BB * HC + BB) * sizeof(float), stream);
    deg_k<<<(EE + 255) / 256, 256, 0, stream>>>(ei, deg);
    scan_part<<<NSB, 256, 0, stream>>>(deg, bsum);
    scan_top<<<1, 128, 0, stream>>>(bsum, boff);
    scan_final<<<NSB, 256, 0, stream>>>(deg, boff, off, cursor, batch, cnt);
    bucket_k<<<(EE + 255) / 256, 256, 0, stream>>>(ei, ea, cursor, esrc, eaf);

    for (int l = 0; l < 3; l++) {
        const int K = (l == 0) ? 64 : 128;
        const float *Wq, *Wk, *Wv, *Wsk, *bq, *bk, *bv, *bs, *We;
        if (l == 0) {
            Wq = (const float*)d_in[5];  bq = (const float*)d_in[6];
            Wk = (const float*)d_in[7];  bk = (const float*)d_in[8];
            Wv = (const float*)d_in[9];  bv = (const float*)d_in[10];
            We = (const float*)d_in[11];
            Wsk= (const float*)d_in[12]; bs = (const float*)d_in[13];
        } else {
            const int j = l - 1;
            Wq = (const float*)d_in[14] + (size_t)j * HC * HC;  bq = (const float*)d_in[15] + j * HC;
            Wk = (const float*)d_in[16] + (size_t)j * HC * HC;  bk = (const float*)d_in[17] + j * HC;
            Wv = (const float*)d_in[18] + (size_t)j * HC * HC;  bv = (const float*)d_in[19] + j * HC;
            We = (const float*)d_in[20] + (size_t)j * 4 * HC;
            Wsk= (const float*)d_in[21] + (size_t)j * HC * HC;  bs = (const float*)d_in[22] + j * HC;
        }

        prep_w<<<(4 * K * 128 + 255) / 256, 256, 0, stream>>>(Wq, Wk, Wv, Wsk, Wt, K);
        if (K == 64)
            gemm_mfma<2, 1><<<NN / 32, 256, 0, stream>>>(Abf, x, Wt, bq, bk, bv, bs, QSb, KVb);
        else
            gemm_mfma<4, 0><<<NN / 32, 256, 0, stream>>>(Abf, x, Wt, bq, bk, bv, bs, QSb, KVb);
        edge_fused<<<NN / 8, 256, 0, stream>>>(esrc, eaf, We, QSb, KVb, off,
                                               Abf, batch, pooled,
                                               l == 2 ? 1 : 0);
    }

    head_k<<<BB / 4, 256, 0, stream>>>(pooled, cnt, rt,
        (const float*)d_in[23], (const float*)d_in[24], (float*)d_out);
}